// Round 24
// baseline (7200.150 us; speedup 1.0000x reference)
//
#include <hip/hip_runtime.h>
#include <math.h>

#define QQ 512
#define NN 1000
#define HHID 1024
#define HPAD 1024   // padded row stride for h trajectories (X uses 1024 too)
#define CCON 128
#define G4 4000
#define LAYERS 8
#define TC 64                       // timestep chunk
#define CHUNKS (QQ / TC)            // 8
#define CONC 4      // pair lanes: 252x1024-thr blocks = 1/CU (residency law)
#define LBLK 63     // blocks per pair, 1024 thr, 1 neuron/wave
#define MAXSTG 32

typedef unsigned long long ull;

__device__ inline float wred_min(float v){ for(int o=32;o;o>>=1) v=fminf(v,__shfl_xor(v,o)); return v; }
__device__ inline float wred_max(float v){ for(int o=32;o;o>>=1) v=fmaxf(v,__shfl_xor(v,o)); return v; }
__device__ inline float wred_sum(float v){ for(int o=32;o;o>>=1) v+=__shfl_xor(v,o); return v; }

// ---------------- generic NT GEMM (X prologue only) ----------------
__global__ __launch_bounds__(256) void gemm_nt(
    const float* __restrict__ A, const float* __restrict__ B,
    const float* __restrict__ bias1,
    float* __restrict__ C, int M, int K, int R, int lda, int ldc) {
  __shared__ float As[16][65];
  __shared__ float Bs[16][65];
  int tid = threadIdx.x;
  int tx = tid & 15, ty = tid >> 4;
  int m0 = blockIdx.y * 64, r0 = blockIdx.x * 64;
  float acc[4][4] = {};
  for (int k0 = 0; k0 < K; k0 += 16) {
#pragma unroll
    for (int i = 0; i < 4; i++) {
      int idx = tid + 256 * i;
      int ml = idx >> 4, kl = idx & 15;
      int m = m0 + ml, k = k0 + kl;
      As[kl][ml] = (m < M && k < K) ? A[(size_t)m * lda + k] : 0.f;
      int r = r0 + ml;
      Bs[kl][ml] = (r < R && k < K) ? B[(size_t)r * K + k] : 0.f;
    }
    __syncthreads();
#pragma unroll
    for (int kk = 0; kk < 16; kk++) {
      float a[4], b[4];
#pragma unroll
      for (int i = 0; i < 4; i++) a[i] = As[kk][ty * 4 + i];
#pragma unroll
      for (int j = 0; j < 4; j++) b[j] = Bs[kk][tx * 4 + j];
#pragma unroll
      for (int i = 0; i < 4; i++)
#pragma unroll
        for (int j = 0; j < 4; j++) acc[i][j] += a[i] * b[j];
    }
    __syncthreads();
  }
#pragma unroll
  for (int i = 0; i < 4; i++) {
    int m = m0 + ty * 4 + i;
    if (m >= M) continue;
#pragma unroll
    for (int j = 0; j < 4; j++) {
      int r = r0 + tx * 4 + j;
      if (r >= R) continue;
      float v = acc[i][j];
      if (bias1) v += bias1[r];
      C[(size_t)m * ldc + r] = v;
    }
  }
}

// -------- persistent self-timed pipeline: all 64 pairs, one dispatch -----
// 252 blocks (4 lanes x 63, 1/CU, all resident). Block (lane,blkid) walks
// its lane's slots of the 19-stage list schedule; readiness is data-driven:
//  - Phase A gate (l>0): poll stamps of the chunk's LAST row (a layer block
//    stores row t only after seeing all of row t-1 -> last row stamped
//    implies full chunk stamped).
//  - recurrence h: stamped 64-bit atoms {stamp=t+1 | fp32}, poll own slot
//    (r21 body polls at every t>0 incl. tt==0 -> handles (l,c-1) tail).
//  - Call: stamped atom {stamp=c+1 | creg}; chunk c polls stamp==c.
// ALL intra-dispatch cross-block reads via relaxed sc1 agent atomics (Hin
// tile fills = 4x8B atomic loads; plain loads could hit stale L2 now).
// No fences (agent acquire fence = buffer_inv, round-3 lesson). W_hh
// preload AFTER Phase A + immediate pin (round-19 spill lesson).
struct PArgs {
  const float* X;
  const float* Wih0; const float* Whh0; const float* bih0; const float* bhh0;
  const float* Wih7; const float* Whh7; const float* bih7; const float* bhh7;
  ull* Hall; ull* Call64;
  int nstages;
  int pl[MAXSTG * CONC]; int pc[MAXSTG * CONC];
};

__global__ __launch_bounds__(1024, 4) void lstm_persist(PArgs a) {
  __shared__ __align__(16) float As[64][68];
  __shared__ __align__(16) float Bs[64][68];
  __shared__ float gl[TC * 64];   // gates: gl[tt*64 + q*16 + w]
  __shared__ float hs[2][1024];   // parity-double-buffered h broadcast
  int blkid = blockIdx.x;
  int lanePair = blockIdx.y;
  int tid = threadIdx.x;
  int wave = tid >> 6, lane = tid & 63;
  int n = blkid * 16 + wave;
  bool active = (n < NN);

  if (tid >= NN) { hs[0][tid] = 0.f; hs[1][tid] = 0.f; }  // pads, once
  __syncthreads();

  for (int s = 0; s < a.nstages; s++) {
    int l = a.pl[s * CONC + lanePair];
    if (l < 0) continue;
    int c = a.pc[s * CONC + lanePair];
    int t0 = c * TC;
    int kin = (l == 0) ? HHID : NN;
    const float* Wih = (l == 0) ? a.Wih0 : a.Wih7 + (size_t)(l - 1) * G4 * NN;
    const float* Whh = (l == 0) ? a.Whh0 : a.Whh7 + (size_t)(l - 1) * G4 * NN;
    const float* b1  = (l == 0) ? a.bih0 : a.bih7 + (size_t)(l - 1) * G4;
    const float* b2  = (l == 0) ? a.bhh0 : a.bhh7 + (size_t)(l - 1) * G4;
    const ull* Hin64 = a.Hall + (size_t)(l - 1) * QQ * HPAD;  // l>0 only
    ull* Hout64 = a.Hall + (size_t)l * QQ * HPAD;
    ull* CallL = a.Call64 + (size_t)l * HPAD;

    // ---- Phase A gate: full input chunk of layer l-1 stamped ----
    if (l > 0) {
      if (tid < NN) {
        const ull* gp = &Hin64[(size_t)(t0 + TC - 1) * HPAD + tid];
        while ((unsigned)(__hip_atomic_load(gp, __ATOMIC_RELAXED,
                                            __HIP_MEMORY_SCOPE_AGENT) >> 32)
               != (unsigned)(t0 + TC))
          __builtin_amdgcn_s_sleep(8);
      }
      __syncthreads();
    }

    // ---- Phase A: tiled GEMM for input-side gates ----
    {
      int ttA = tid >> 4;
      int w16 = tid & 15;
      int nn = blkid * 16 + w16;
      float accq[4] = {0.f, 0.f, 0.f, 0.f};
      float pbq[4];
#pragma unroll
      for (int q = 0; q < 4; q++)
        pbq[q] = (nn < NN) ? b1[q * NN + nn] + b2[q * NN + nn] : 0.f;
      int ldr = tid >> 4, ldc4 = tid & 15;
      int qb = ldr >> 4, nb = blkid * 16 + (ldr & 15);
      for (int k0 = 0; k0 < kin; k0 += 64) {
        int k = k0 + ldc4 * 4;
        float4 av;
        if (l == 0) {                      // X: prev-dispatch, plain float4
          av = *(const float4*)&a.X[(size_t)(t0 + ldr) * HPAD + k];
        } else {                           // intra-dispatch: sc1 8B atomics
          float f0 = 0.f, f1 = 0.f, f2 = 0.f, f3 = 0.f;
          const ull* rowp = &Hin64[(size_t)(t0 + ldr) * HPAD];
          if (k < kin)
            f0 = __uint_as_float((unsigned)__hip_atomic_load(
                &rowp[k], __ATOMIC_RELAXED, __HIP_MEMORY_SCOPE_AGENT));
          if (k + 1 < kin)
            f1 = __uint_as_float((unsigned)__hip_atomic_load(
                &rowp[k + 1], __ATOMIC_RELAXED, __HIP_MEMORY_SCOPE_AGENT));
          if (k + 2 < kin)
            f2 = __uint_as_float((unsigned)__hip_atomic_load(
                &rowp[k + 2], __ATOMIC_RELAXED, __HIP_MEMORY_SCOPE_AGENT));
          if (k + 3 < kin)
            f3 = __uint_as_float((unsigned)__hip_atomic_load(
                &rowp[k + 3], __ATOMIC_RELAXED, __HIP_MEMORY_SCOPE_AGENT));
          av.x = f0; av.y = f1; av.z = f2; av.w = f3;
        }
        *(float4*)&As[ldr][ldc4 * 4] = av;
        float4 bv = {0.f, 0.f, 0.f, 0.f};
        if (nb < NN) {
          if (k + 3 < kin) {
            bv = *(const float4*)&Wih[(size_t)(qb * NN + nb) * kin + k];
          } else {
            float* f = (float*)&bv;
#pragma unroll
            for (int e = 0; e < 4; e++)
              if (k + e < kin) f[e] = Wih[(size_t)(qb * NN + nb) * kin + k + e];
          }
        }
        *(float4*)&Bs[ldr][ldc4 * 4] = bv;
        __syncthreads();
#pragma unroll
        for (int kk = 0; kk < 64; kk += 4) {
          float4 aa = *(const float4*)&As[ttA][kk];
#pragma unroll
          for (int q = 0; q < 4; q++) {
            float4 b = *(const float4*)&Bs[q * 16 + w16][kk];
            accq[q] += aa.x * b.x + aa.y * b.y + aa.z * b.z + aa.w * b.w;
          }
        }
        __syncthreads();
      }
#pragma unroll
      for (int q = 0; q < 4; q++)
        gl[ttA * 64 + q * 16 + w16] = accq[q] + pbq[q];
    }

    // ---- Phase B: W_hh preload + immediate pin ----
    float wreg[4][16];
    if (active) {
#pragma unroll
      for (int q = 0; q < 4; q++) {
        const float* wr = Whh + (size_t)(q * NN + n) * NN;
#pragma unroll
        for (int it = 0; it < 16; it++) {
          int k = it * 64 + lane;
          wreg[q][it] = (k < NN) ? wr[k] : 0.f;
        }
      }
    } else {
#pragma unroll
      for (int q = 0; q < 4; q++)
#pragma unroll
        for (int it = 0; it < 16; it++) wreg[q][it] = 0.f;
    }
#pragma unroll
    for (int q = 0; q < 4; q++)
#pragma unroll
      for (int it = 0; it < 16; it++)
        asm volatile("" : "+v"(wreg[q][it]));

    __syncthreads();  // gl complete

    // ---- cell state: stamped Call handoff ----
    float creg = 0.f;
    if (t0 > 0 && active) {
      const ull* cp = &CallL[n];   // wave-uniform poll (one line)
      for (;;) {
        ull v = __hip_atomic_load(cp, __ATOMIC_RELAXED,
                                  __HIP_MEMORY_SCOPE_AGENT);
        if ((unsigned)(v >> 32) == (unsigned)c) {
          creg = __uint_as_float((unsigned)v);
          break;
        }
        __builtin_amdgcn_s_sleep(2);
      }
    }

    // ---- recurrence: stamped-poll, ONE barrier per step ----
    for (int tt = 0; tt < TC; tt++) {
      int t = t0 + tt;
      float* hb = hs[t & 1];
      if (t > 0 && tid < NN) {
        const ull* src = Hout64 + (size_t)(t - 1) * HPAD + tid;
        for (;;) {
          ull v = __hip_atomic_load(src, __ATOMIC_RELAXED,
                                    __HIP_MEMORY_SCOPE_AGENT);
          if ((unsigned)(v >> 32) == (unsigned)t) {
            hb[tid] = __uint_as_float((unsigned)v);
            break;
          }
          __builtin_amdgcn_s_sleep(1);
        }
      }
      __syncthreads();
      if (active) {
        float g0 = gl[tt * 64 + wave];
        float g1 = gl[tt * 64 + 16 + wave];
        float g2 = gl[tt * 64 + 32 + wave];
        float g3 = gl[tt * 64 + 48 + wave];
        if (t > 0) {
          float a0 = 0.f, a1 = 0.f, a2 = 0.f, a3 = 0.f;
#pragma unroll
          for (int it = 0; it < 16; it++) {
            float hv = hb[it * 64 + lane];
            a0 += wreg[0][it] * hv;
            a1 += wreg[1][it] * hv;
            a2 += wreg[2][it] * hv;
            a3 += wreg[3][it] * hv;
          }
#pragma unroll
          for (int o = 32; o; o >>= 1) {
            a0 += __shfl_xor(a0, o);
            a1 += __shfl_xor(a1, o);
            a2 += __shfl_xor(a2, o);
            a3 += __shfl_xor(a3, o);
          }
          g0 += a0; g1 += a1; g2 += a2; g3 += a3;
        }
        float ii = 1.f / (1.f + expf(-g0));
        float ff = 1.f / (1.f + expf(-g1));
        float gg = tanhf(g2);
        float oo = 1.f / (1.f + expf(-g3));
        creg = ff * creg + ii * gg;
        float h = oo * tanhf(creg);
        if (lane == 0) {
          ull pkt = ((ull)(unsigned)(t + 1) << 32) | (ull)__float_as_uint(h);
          __hip_atomic_store(&Hout64[(size_t)t * HPAD + n], pkt,
                             __ATOMIC_RELAXED, __HIP_MEMORY_SCOPE_AGENT);
        }
      }
    }
    // publish cell state for chunk c+1 (stamp = c+1)
    if (active && lane == 0) {
      ull pkt = ((ull)(unsigned)(c + 1) << 32) | (ull)__float_as_uint(creg);
      __hip_atomic_store(&CallL[n], pkt, __ATOMIC_RELAXED,
                         __HIP_MEMORY_SCOPE_AGENT);
    }
    __syncthreads();  // LDS quiesced before next pair
  }
}

// ---------------- epilogue (reads stamped H7, low word) ----------------
__global__ __launch_bounds__(256) void epilogue_out(
    const ull* __restrict__ H7,     // [QQ, HPAD] stamped
    const float* __restrict__ Wlin, const float* __restrict__ blin,
    const int* __restrict__ ccol, const float* __restrict__ Dnz,
    float* __restrict__ out,        // [QQ, NN]
    float* __restrict__ irbuf, float* __restrict__ mnirbuf) {
  int t = blockIdx.x, tid = threadIdx.x;
  int wave = tid >> 6, lane = tid & 63;
  __shared__ float hbuf[NN];
  __shared__ float smin[4], smax[4];
  __shared__ float bc[2];
  float lmin = 3.4e38f, lmax = -3.4e38f;
  for (int i = tid; i < NN; i += 256) {
    float v = __uint_as_float((unsigned)H7[(size_t)t * HPAD + i]);
    hbuf[i] = v;
    lmin = fminf(lmin, v); lmax = fmaxf(lmax, v);
  }
  lmin = wred_min(lmin); lmax = wred_max(lmax);
  if (lane == 0) { smin[wave] = lmin; smax[wave] = lmax; }
  __syncthreads();
  if (tid == 0) {
    bc[0] = fminf(fminf(smin[0], smin[1]), fminf(smin[2], smin[3]));
    bc[1] = fmaxf(fmaxf(smax[0], smax[1]), fmaxf(smax[2], smax[3]));
  }
  __syncthreads();
  float hmn = bc[0], hmx = bc[1];
  float clo = 3.4e38f, chi = -3.4e38f;
  if (tid < CCON) {
    float w = Wlin[tid], b = blin[tid];
    clo = b + fminf(w * hmn, w * hmx);
    chi = b + fmaxf(w * hmn, w * hmx);
  }
  clo = wred_min(clo); chi = wred_max(chi);
  __syncthreads();  // smin/smax reused below
  if (lane == 0) { smin[wave] = clo; smax[wave] = chi; }
  __syncthreads();
  if (tid == 0) {
    float mn = fminf(fminf(smin[0], smin[1]), fminf(smin[2], smin[3]));
    float mx = fmaxf(fmaxf(smax[0], smax[1]), fmaxf(smax[2], smax[3]));
    float ir = 1.f / (mx - mn);
    bc[0] = mn; bc[1] = ir;
    irbuf[t] = ir;
    mnirbuf[t] = mn * ir;
  }
  __syncthreads();
  float mn = bc[0], ir = bc[1];
  int cc = ccol[t];
  float wcc = Wlin[cc], bcc = blin[cc], d = Dnz[t];
  for (int n = tid; n < NN; n += 256) {
    float s = (hbuf[n] * wcc + bcc - mn) * ir;
    out[(size_t)t * NN + n] = fmaxf(0.25f, 1.f - expf(-10.f * (s - d)));
  }
}

__global__ void reduce_scalars(const float* __restrict__ ir,
                               const float* __restrict__ mnir,
                               float* __restrict__ scal) {
  int tid = threadIdx.x;  // 512
  int wave = tid >> 6, lane = tid & 63;
  __shared__ float s1[8], s2[8];
  float a = ir[tid], b = mnir[tid];
  a = wred_sum(a); b = wred_sum(b);
  if (lane == 0) { s1[wave] = a; s2[wave] = b; }
  __syncthreads();
  if (tid == 0) {
    float A = 0.f, B = 0.f;
    for (int i = 0; i < 8; i++) { A += s1[i]; B += s2[i]; }
    scal[0] = A; scal[1] = B;
  }
}

__global__ void accum_A(const ull* __restrict__ H7,
                        const float* __restrict__ ir,
                        float* __restrict__ Avec) {
  int n = blockIdx.x * 256 + threadIdx.x;
  if (n < NN) {
    float acc = 0.f;
    for (int t = 0; t < QQ; t++)
      acc += __uint_as_float((unsigned)H7[(size_t)t * HPAD + n]) * ir[t];
    Avec[n] = acc;
  }
}

__global__ void skills_out(const float* __restrict__ Avec,
                           const float* __restrict__ Wlin,
                           const float* __restrict__ blin,
                           const float* __restrict__ scal,
                           float* __restrict__ out) {  // [NN, CCON]
  int idx = blockIdx.x * 256 + threadIdx.x;
  if (idx < NN * CCON) {
    int n = idx >> 7, c = idx & 127;
    out[idx] = (Wlin[c] * Avec[n] + blin[c] * scal[0] - scal[1]) * (1.f / (float)QQ);
  }
}

extern "C" void kernel_launch(void* const* d_in, const int* in_sizes, int n_in,
                              void* d_out, int out_size, void* d_ws, size_t ws_size,
                              hipStream_t stream) {
  const float* inputs = (const float*)d_in[0];
  const int*   ccol   = (const int*)d_in[1];
  const float* W_inp  = (const float*)d_in[2];
  const float* b_inp  = (const float*)d_in[3];
  const float* W_ih0  = (const float*)d_in[4];
  const float* W_hh0  = (const float*)d_in[5];
  const float* b_ih0  = (const float*)d_in[6];
  const float* b_hh0  = (const float*)d_in[7];
  const float* W_ih   = (const float*)d_in[8];   // [7, 4000, 1000]
  const float* W_hh   = (const float*)d_in[9];   // [7, 4000, 1000]
  const float* b_ih   = (const float*)d_in[10];  // [7, 4000]
  const float* b_hh   = (const float*)d_in[11];  // [7, 4000]
  const float* W_lin  = (const float*)d_in[12];  // [128]
  const float* b_lin  = (const float*)d_in[13];  // [128]
  const float* D_nz   = (const float*)d_in[14];  // [512]

  float* ws = (float*)d_ws;
  float* X     = ws;                          // [512,1024] fp32
  ull*   Hall  = (ull*)(X + (size_t)QQ * HPAD); // [8][512][1024] stamped
  ull*   Call64 = Hall + (size_t)LAYERS * QQ * HPAD;  // [8][1024] stamped
  float* tail  = (float*)(Call64 + (size_t)LAYERS * HPAD);
  float* irb   = tail;                        // [512]
  float* mnir  = irb + QQ;                    // [512]
  float* Avec  = mnir + QQ;                   // [1024]
  float* scal  = Avec + 1024;                 // [2] (+pad)

  float* out_main   = (float*)d_out;            // [512,1000]
  float* out_skills = (float*)d_out + QQ * NN;  // [1000,128]

  // Zero ALL stamps (Hall + Call64) every launch (graph-captured).
  hipMemsetAsync(Hall, 0,
                 ((size_t)LAYERS * QQ * HPAD + LAYERS * HPAD) * sizeof(ull),
                 stream);

  // X = inputs @ W_inp^T + b_inp   (M=512, K=1000, R=1024, ldc=HPAD)
  gemm_nt<<<dim3(HPAD / 64, QQ / 64), 256, 0, stream>>>(
      inputs, W_inp, b_inp, X, QQ, NN, HPAD, NN, HPAD);

  // Build the 19-stage list schedule (CONC=4) and run it self-timed in ONE
  // persistent dispatch.
  PArgs pa;
  pa.X = X;
  pa.Wih0 = W_ih0; pa.Whh0 = W_hh0; pa.bih0 = b_ih0; pa.bhh0 = b_hh0;
  pa.Wih7 = W_ih; pa.Whh7 = W_hh; pa.bih7 = b_ih; pa.bhh7 = b_hh;
  pa.Hall = Hall; pa.Call64 = Call64;
  for (int i = 0; i < MAXSTG * CONC; i++) { pa.pl[i] = -1; pa.pc[i] = -1; }
  {
    bool donep[LAYERS][CHUNKS] = {};
    int remaining = LAYERS * CHUNKS;
    int s = 0;
    while (remaining > 0 && s < MAXSTG) {
      bool sel[LAYERS][CHUNKS] = {};
      int np = 0;
      int spl[CONC], spc[CONC];
      for (int pick = 0; pick < CONC; pick++) {
        int bl = -1, bc = -1, bkey = 1 << 30;
        for (int l = 0; l < LAYERS; l++)
          for (int c = 0; c < CHUNKS; c++) {
            if (donep[l][c] || sel[l][c]) continue;
            if (l > 0 && !donep[l - 1][c]) continue;
            if (c > 0 && !donep[l][c - 1]) continue;
            int key = (l + c) * 16 + (LAYERS - 1 - l);
            if (key < bkey) { bkey = key; bl = l; bc = c; }
          }
        if (bl < 0) break;
        sel[bl][bc] = true; spl[np] = bl; spc[np] = bc; np++;
      }
      for (int i = 0; i < np; i++) {
        pa.pl[s * CONC + i] = spl[i];
        pa.pc[s * CONC + i] = spc[i];
        donep[spl[i]][spc[i]] = true;
      }
      remaining -= np;
      s++;
    }
    pa.nstages = s;
  }
  lstm_persist<<<dim3(LBLK, CONC), 1024, 0, stream>>>(pa);

  const ull* H7 = Hall + (size_t)7 * QQ * HPAD;
  epilogue_out<<<QQ, 256, 0, stream>>>(H7, W_lin, b_lin, ccol, D_nz,
                                       out_main, irb, mnir);
  reduce_scalars<<<1, 512, 0, stream>>>(irb, mnir, scal);
  accum_A<<<4, 256, 0, stream>>>(H7, irb, Avec);
  skills_out<<<(NN * CCON) / 256, 256, 0, stream>>>(Avec, W_lin, b_lin, scal,
                                                    out_skills);
}